// Round 10
// baseline (316.225 us; speedup 1.0000x reference)
//
#include <hip/hip_runtime.h>
#include <math.h>

constexpr int IMH = 2048, IMW = 2048, NB = 4;
constexpr int NPIX = NB * IMH * IMW;           // 16777216
constexpr unsigned KSEL = 8388607u;            // floor(0.5*(NPIX-1)) -> quantile 'lower'

__device__ __forceinline__ unsigned f2u(float f) {
    unsigned b = __float_as_uint(f);
    return (b & 0x80000000u) ? ~b : (b | 0x80000000u);
}

__device__ __forceinline__ void gauss7(float* a) {
    const double g0 = 0.8352702114112720;   // exp(-0.18)
    const double g1 = 0.9231163463866358;   // exp(-0.08)
    const double g2 = 0.9801986733067553;   // exp(-0.02)
    const double s = 2.0 * (g0 + g1 + g2) + 1.0;
    const double inv = 1.0 / s;
    a[0] = a[6] = (float)(g0 * inv);
    a[1] = a[5] = (float)(g1 * inv);
    a[2] = a[4] = (float)(g2 * inv);
    a[3] = (float)inv;
}

__device__ __forceinline__ float2 fmax2(float2 a, float2 b) {
    return make_float2(fmaxf(a.x, b.x), fmaxf(a.y, b.y));
}

// ================= STREAMING PATH (pass A / pass B) =================
// NUMERICS CONTRACT (r8/r9, passed): ix parens = column sums cS=w0+2*w1+w2;
// iy parens = 1,2,1 row sums. Products: t=a[d]*ix; xx+=t*ix; xy+=t*iy;
// yy+=(a[d]*iy)*iy, d ascending. v-blur: acc += a[d]*v, d ascending. Same R formula.

// pass A: sobel + products + h-blur for one sobel row r, 4 cols. No LDS, no barriers.
__global__ void passA(const float* __restrict__ x, float* __restrict__ STH,
                      int sr0, int nsr, size_t ps) {
    const int tid = threadIdx.x;
    const int G = blockIdx.x * 16 + (tid & 15);      // col group 0..511 (4 cols each)
    const int srow = blockIdx.y * 16 + (tid >> 4);   // row within STH band
    if (srow >= nsr) return;
    const int b = blockIdx.z;
    const int r = sr0 + srow;                        // global sobel row
    float* out0 = STH + ((size_t)b * 3 + 0) * ps + (size_t)srow * IMW + 4 * G;
    float* out1 = STH + ((size_t)b * 3 + 1) * ps + (size_t)srow * IMW + 4 * G;
    float* out2 = STH + ((size_t)b * 3 + 2) * ps + (size_t)srow * IMW + 4 * G;
    if ((unsigned)r >= (unsigned)IMH) {              // gauss zero-padding rows
        *(float4*)out0 = make_float4(0.f, 0.f, 0.f, 0.f);
        *(float4*)out1 = make_float4(0.f, 0.f, 0.f, 0.f);
        *(float4*)out2 = make_float4(0.f, 0.f, 0.f, 0.f);
        return;
    }
    const float* xb = x + (size_t)b * IMH * IMW;
    const int cb = 4 * G - 4;                        // first x col of 12-wide window
    float w0[12], w1[12], w2[12];
    const bool fast = (cb >= 0) && (cb + 12 <= IMW) && (r >= 1) && (r <= IMH - 2);
    if (fast) {
        const float* p0 = xb + (size_t)(r - 1) * IMW + cb;
        const float* p1 = p0 + IMW;
        const float* p2 = p1 + IMW;
        float4 A0 = *(const float4*)(p0), B0 = *(const float4*)(p0 + 4), C0 = *(const float4*)(p0 + 8);
        float4 A1 = *(const float4*)(p1), B1 = *(const float4*)(p1 + 4), C1 = *(const float4*)(p1 + 8);
        float4 A2 = *(const float4*)(p2), B2 = *(const float4*)(p2 + 4), C2 = *(const float4*)(p2 + 8);
        w0[0]=A0.x; w0[1]=A0.y; w0[2]=A0.z; w0[3]=A0.w; w0[4]=B0.x; w0[5]=B0.y; w0[6]=B0.z; w0[7]=B0.w; w0[8]=C0.x; w0[9]=C0.y; w0[10]=C0.z; w0[11]=C0.w;
        w1[0]=A1.x; w1[1]=A1.y; w1[2]=A1.z; w1[3]=A1.w; w1[4]=B1.x; w1[5]=B1.y; w1[6]=B1.z; w1[7]=B1.w; w1[8]=C1.x; w1[9]=C1.y; w1[10]=C1.z; w1[11]=C1.w;
        w2[0]=A2.x; w2[1]=A2.y; w2[2]=A2.z; w2[3]=A2.w; w2[4]=B2.x; w2[5]=B2.y; w2[6]=B2.z; w2[7]=B2.w; w2[8]=C2.x; w2[9]=C2.y; w2[10]=C2.z; w2[11]=C2.w;
    } else {
        #pragma unroll
        for (int j = 0; j < 12; ++j) {
            int gx = cb + j;
            bool cok = (unsigned)gx < (unsigned)IMW;
            w0[j] = (cok && r - 1 >= 0) ? xb[(size_t)(r - 1) * IMW + gx] : 0.f;
            w1[j] = cok ? xb[(size_t)r * IMW + gx] : 0.f;
            w2[j] = (cok && r + 1 < IMH) ? xb[(size_t)(r + 1) * IMW + gx] : 0.f;
        }
    }
    float cS[12];
    #pragma unroll
    for (int j = 0; j < 12; ++j) cS[j] = w0[j] + 2.0f * w1[j] + w2[j];
    float ix[10], iy[10];
    #pragma unroll
    for (int j = 0; j < 10; ++j) {
        ix[j] = cS[j + 2] - cS[j];
        float rS2 = w2[j] + 2.0f * w2[j + 1] + w2[j + 2];
        float rS0 = w0[j] + 2.0f * w0[j + 1] + w0[j + 2];
        iy[j] = rS2 - rS0;
    }
    if (G == 0 || G == 511) {                        // sobel-col zero padding (gauss pad)
        #pragma unroll
        for (int j = 0; j < 10; ++j) {
            int gx = cb + 1 + j;
            if (!((unsigned)gx < (unsigned)IMW)) { ix[j] = 0.f; iy[j] = 0.f; }
        }
    }
    float a[7]; gauss7(a);
    float sxx[4], syy[4], sxy[4];
    #pragma unroll
    for (int k = 0; k < 4; ++k) {
        float xx = 0.f, yy = 0.f, xy = 0.f;
        #pragma unroll
        for (int d = 0; d < 7; ++d) {
            float vx = ix[k + d], vy = iy[k + d];
            float t = a[d] * vx;
            xx += t * vx;
            xy += t * vy;
            yy += (a[d] * vy) * vy;
        }
        sxx[k] = xx; syy[k] = yy; sxy[k] = xy;
    }
    *(float4*)out0 = make_float4(sxx[0], sxx[1], sxx[2], sxx[3]);
    *(float4*)out1 = make_float4(syy[0], syy[1], syy[2], syy[3]);
    *(float4*)out2 = make_float4(sxy[0], sxy[1], sxy[2], sxy[3]);
}

// pass B: v-blur + R + hist1 (2048 bins). Streaming float2 loads, LDS only for hist.
__global__ void passB(const float* __restrict__ STH, float* __restrict__ Rout,
                      unsigned* __restrict__ hist, int band_start, size_t ps) {
    __shared__ unsigned LH[2048];
    const int tid = threadIdx.x;
    for (int i = tid; i < 2048; i += 256) LH[i] = 0u;
    const int p = blockIdx.x * 256 + tid;            // col pair 0..1023
    const int r0 = band_start + blockIdx.y * 8;      // first output row
    const int b = blockIdx.z;
    const int srbase = blockIdx.y * 8;               // window row 0 in band coords
    const float* pl0 = STH + ((size_t)b * 3 + 0) * ps + (size_t)srbase * IMW + 2 * p;
    const float* pl1 = STH + ((size_t)b * 3 + 1) * ps + (size_t)srbase * IMW + 2 * p;
    const float* pl2 = STH + ((size_t)b * 3 + 2) * ps + (size_t)srbase * IMW + 2 * p;
    float2 vxx[14], vyy[14], vxy[14];
    #pragma unroll
    for (int t = 0; t < 14; ++t) {
        vxx[t] = *(const float2*)&pl0[(size_t)t * IMW];
        vyy[t] = *(const float2*)&pl1[(size_t)t * IMW];
        vxy[t] = *(const float2*)&pl2[(size_t)t * IMW];
    }
    float a[7]; gauss7(a);
    __syncthreads();                                 // LH zeroed
    float* Rb = Rout + (size_t)b * IMH * IMW + (size_t)r0 * IMW + 2 * p;
    #pragma unroll
    for (int j = 0; j < 8; ++j) {
        float sxxA = 0.f, syyA = 0.f, sxyA = 0.f;
        float sxxB = 0.f, syyB = 0.f, sxyB = 0.f;
        #pragma unroll
        for (int d = 0; d < 7; ++d) {
            sxxA += a[d] * vxx[j + d].x;  sxxB += a[d] * vxx[j + d].y;
            syyA += a[d] * vyy[j + d].x;  syyB += a[d] * vyy[j + d].y;
            sxyA += a[d] * vxy[j + d].x;  sxyB += a[d] * vxy[j + d].y;
        }
        float trA = sxxA + syyA;
        float RA = sxxA * syyA - sxyA * sxyA - 0.05f * trA * trA;
        float trB = sxxB + syyB;
        float RB = sxxB * syyB - sxyB * sxyB - 0.05f * trB * trB;
        *(float2*)&Rb[(size_t)j * IMW] = make_float2(RA, RB);
        atomicAdd(&LH[f2u(RA) >> 21], 1u);
        atomicAdd(&LH[f2u(RB) >> 21], 1u);
    }
    __syncthreads();
    const unsigned slot = ((blockIdx.z * gridDim.y + blockIdx.y) * gridDim.x + blockIdx.x) & 7u;
    for (int i = tid; i < 2048; i += 256) {
        unsigned c = LH[i];
        if (c) atomicAdd(&hist[i * 8 + slot], c);
    }
}

// ================= FALLBACK: r9 fused harris_R (proven, 186 us) =================
template<bool CHK>
__device__ __forceinline__ void hblur_fused(const float* SX, float* STH, const float* a,
                                            int r, int g, int x0, int y0) {
    const float* p0 = SX + r * 72 + 4 * g;
    const float* p1 = p0 + 72;
    const float* p2 = p1 + 72;
    float4 A0 = *(const float4*)(p0), B0 = *(const float4*)(p0 + 4), C0 = *(const float4*)(p0 + 8);
    float4 A1 = *(const float4*)(p1), B1 = *(const float4*)(p1 + 4), C1 = *(const float4*)(p1 + 8);
    float4 A2 = *(const float4*)(p2), B2 = *(const float4*)(p2 + 4), C2 = *(const float4*)(p2 + 8);
    float w0[12] = {A0.x, A0.y, A0.z, A0.w, B0.x, B0.y, B0.z, B0.w, C0.x, C0.y, C0.z, C0.w};
    float w1[12] = {A1.x, A1.y, A1.z, A1.w, B1.x, B1.y, B1.z, B1.w, C1.x, C1.y, C1.z, C1.w};
    float w2[12] = {A2.x, A2.y, A2.z, A2.w, B2.x, B2.y, B2.z, B2.w, C2.x, C2.y, C2.z, C2.w};
    float cS[12];
    #pragma unroll
    for (int j = 0; j < 12; ++j) cS[j] = w0[j] + 2.0f * w1[j] + w2[j];
    float ix[10], iy[10];
    #pragma unroll
    for (int j = 0; j < 10; ++j) {
        ix[j] = cS[j + 2] - cS[j];
        float rS2 = w2[j] + 2.0f * w2[j + 1] + w2[j + 2];
        float rS0 = w0[j] + 2.0f * w0[j + 1] + w0[j + 2];
        iy[j] = rS2 - rS0;
        if (CHK) {
            int gy = y0 - 3 + r, gx = x0 - 3 + (4 * g + j);
            if (!((unsigned)gy < (unsigned)IMH && (unsigned)gx < (unsigned)IMW)) {
                ix[j] = 0.f; iy[j] = 0.f;
            }
        }
    }
    float sxx[4], syy[4], sxy[4];
    #pragma unroll
    for (int k = 0; k < 4; ++k) {
        float xx = 0.f, yy = 0.f, xy = 0.f;
        #pragma unroll
        for (int d = 0; d < 7; ++d) {
            float vx = ix[k + d], vy = iy[k + d];
            float t = a[d] * vx;
            xx += t * vx;
            xy += t * vy;
            yy += (a[d] * vy) * vy;
        }
        sxx[k] = xx; syy[k] = yy; sxy[k] = xy;
    }
    *(float4*)&STH[r * 64 + 4 * g]        = make_float4(sxx[0], sxx[1], sxx[2], sxx[3]);
    *(float4*)&STH[2432 + r * 64 + 4 * g] = make_float4(syy[0], syy[1], syy[2], syy[3]);
    *(float4*)&STH[4864 + r * 64 + 4 * g] = make_float4(sxy[0], sxy[1], sxy[2], sxy[3]);
}

__launch_bounds__(256, 4)
__global__ void harris_R(const float* __restrict__ x, float* __restrict__ Rout,
                         unsigned* __restrict__ hist) {
    __shared__ __align__(16) float smem[10176];
    float* STH = smem;
    float* SX = smem + 7296;
    unsigned* LH = (unsigned*)(smem + 7296);

    const int tid = threadIdx.x;
    const int tx = tid & 63, ty = tid >> 6;
    const int x0 = blockIdx.x * 64, y0 = blockIdx.y * 32, b = blockIdx.z;
    const float* xb = x + (size_t)b * IMH * IMW;
    const bool interior = (x0 >= 4) && (x0 + 68 <= IMW) && (y0 >= 4) && (y0 + 36 <= IMH);

    if (interior) {
        const float* xp = xb + (size_t)(y0 - 4) * IMW + (x0 - 4);
        #pragma unroll
        for (int k = 0; k < 3; ++k) {
            int i = tid + k * 256;
            if (i < 720) {
                int r = i / 18, c4 = i - r * 18;
                *(float4*)&SX[r * 72 + 4 * c4] = *(const float4*)&xp[(size_t)r * IMW + 4 * c4];
            }
        }
    } else {
        for (int i = tid; i < 2880; i += 256) {
            int r = i / 72, c = i - r * 72;
            int gy = y0 - 4 + r, gx = x0 - 4 + c;
            float v = 0.f;
            if ((unsigned)gy < (unsigned)IMH && (unsigned)gx < (unsigned)IMW)
                v = xb[(size_t)gy * IMW + gx];
            SX[r * 72 + c] = v;
        }
    }
    __syncthreads();

    float a[7]; gauss7(a);

    if (interior) {
        #pragma unroll
        for (int k = 0; k < 3; ++k) {
            int i = tid + k * 256;
            if (i < 608) { int r = i >> 4, g = i & 15; hblur_fused<false>(SX, STH, a, r, g, x0, y0); }
        }
    } else {
        #pragma unroll
        for (int k = 0; k < 3; ++k) {
            int i = tid + k * 256;
            if (i < 608) { int r = i >> 4, g = i & 15; hblur_fused<true>(SX, STH, a, r, g, x0, y0); }
        }
    }
    __syncthreads();

    for (int i = tid; i < 2048; i += 256) LH[i] = 0u;

    float vxx[14], vyy[14], vxy[14];
    {
        const float* base = STH + (8 * ty) * 64 + tx;
        #pragma unroll
        for (int t = 0; t < 14; ++t) {
            vxx[t] = base[t * 64];
            vyy[t] = base[2432 + t * 64];
            vxy[t] = base[4864 + t * 64];
        }
    }
    float rv[8];
    float* Rb = Rout + (size_t)b * IMH * IMW + (size_t)y0 * IMW + x0;
    #pragma unroll
    for (int j = 0; j < 8; ++j) {
        float sxx = 0.f, syy = 0.f, sxy = 0.f;
        #pragma unroll
        for (int d = 0; d < 7; ++d) {
            sxx += a[d] * vxx[j + d];
            syy += a[d] * vyy[j + d];
            sxy += a[d] * vxy[j + d];
        }
        float tr = sxx + syy;
        float R = sxx * syy - sxy * sxy - 0.05f * tr * tr;
        rv[j] = R;
        Rb[(size_t)(8 * ty + j) * IMW + tx] = R;
    }
    __syncthreads();

    #pragma unroll
    for (int j = 0; j < 8; ++j) atomicAdd(&LH[f2u(rv[j]) >> 21], 1u);
    __syncthreads();

    const unsigned slot = ((blockIdx.z * gridDim.y + blockIdx.y) * gridDim.x + blockIdx.x) & 7u;
    for (int i = tid; i < 2048; i += 256) {
        unsigned c = LH[i];
        if (c) atomicAdd(&hist[i * 8 + slot], c);
    }
}

// ---------- median: radix select 11+12+9 bits; pass 1 fused above (8-slot) ----------
__global__ void zero_kernel(unsigned* __restrict__ p, int n, int kidx, unsigned kval) {
    int i = blockIdx.x * blockDim.x + threadIdx.x;
    if (i < n) p[i] = (i == kidx) ? kval : 0u;
}

__global__ void hist2_kernel(const float* __restrict__ R, unsigned* __restrict__ hist,
                             const unsigned* __restrict__ sel) {
    __shared__ unsigned lh[4096];
    for (int i = threadIdx.x; i < 4096; i += 256) lh[i] = 0u;
    __syncthreads();
    const unsigned pref = sel[1];
    const float4* R4 = (const float4*)R;
    const int n4 = NPIX / 4;
    for (int i = (blockIdx.x * 256 + threadIdx.x) * 2; i < n4; i += gridDim.x * 512) {
        float4 v0 = R4[i];
        float4 v1 = R4[i + 1];
        unsigned u;
        u = f2u(v0.x); if ((u >> 21) == pref) atomicAdd(&lh[(u >> 9) & 0xFFFu], 1u);
        u = f2u(v0.y); if ((u >> 21) == pref) atomicAdd(&lh[(u >> 9) & 0xFFFu], 1u);
        u = f2u(v0.z); if ((u >> 21) == pref) atomicAdd(&lh[(u >> 9) & 0xFFFu], 1u);
        u = f2u(v0.w); if ((u >> 21) == pref) atomicAdd(&lh[(u >> 9) & 0xFFFu], 1u);
        u = f2u(v1.x); if ((u >> 21) == pref) atomicAdd(&lh[(u >> 9) & 0xFFFu], 1u);
        u = f2u(v1.y); if ((u >> 21) == pref) atomicAdd(&lh[(u >> 9) & 0xFFFu], 1u);
        u = f2u(v1.z); if ((u >> 21) == pref) atomicAdd(&lh[(u >> 9) & 0xFFFu], 1u);
        u = f2u(v1.w); if ((u >> 21) == pref) atomicAdd(&lh[(u >> 9) & 0xFFFu], 1u);
    }
    __syncthreads();
    for (int i = threadIdx.x; i < 4096; i += 256) { unsigned c = lh[i]; if (c) atomicAdd(&hist[i], c); }
}

__global__ void hist3_kernel(const float* __restrict__ R, unsigned* __restrict__ hist,
                             const unsigned* __restrict__ sel) {
    __shared__ unsigned lh[512];
    if (threadIdx.x < 256) { lh[threadIdx.x] = 0u; lh[threadIdx.x + 256] = 0u; }
    __syncthreads();
    const unsigned pref = sel[1];
    const float4* R4 = (const float4*)R;
    const int n4 = NPIX / 4;
    for (int i = (blockIdx.x * 256 + threadIdx.x) * 2; i < n4; i += gridDim.x * 512) {
        float4 v0 = R4[i];
        float4 v1 = R4[i + 1];
        unsigned u;
        u = f2u(v0.x); if ((u >> 9) == pref) atomicAdd(&lh[u & 0x1FFu], 1u);
        u = f2u(v0.y); if ((u >> 9) == pref) atomicAdd(&lh[u & 0x1FFu], 1u);
        u = f2u(v0.z); if ((u >> 9) == pref) atomicAdd(&lh[u & 0x1FFu], 1u);
        u = f2u(v0.w); if ((u >> 9) == pref) atomicAdd(&lh[u & 0x1FFu], 1u);
        u = f2u(v1.x); if ((u >> 9) == pref) atomicAdd(&lh[u & 0x1FFu], 1u);
        u = f2u(v1.y); if ((u >> 9) == pref) atomicAdd(&lh[u & 0x1FFu], 1u);
        u = f2u(v1.z); if ((u >> 9) == pref) atomicAdd(&lh[u & 0x1FFu], 1u);
        u = f2u(v1.w); if ((u >> 9) == pref) atomicAdd(&lh[u & 0x1FFu], 1u);
    }
    __syncthreads();
    if (threadIdx.x < 256) {
        unsigned c = lh[threadIdx.x]; if (c) atomicAdd(&hist[threadIdx.x], c);
        c = lh[threadIdx.x + 256]; if (c) atomicAdd(&hist[threadIdx.x + 256], c);
    }
}

__global__ void select_kernel(const unsigned* __restrict__ hist, unsigned* __restrict__ sel,
                              int bpt, int bits, int final_stage, int slots) {
    __shared__ unsigned part[256];
    __shared__ unsigned grp[16];
    __shared__ int chs;
    __shared__ unsigned runs;
    const int t = threadIdx.x;
    const unsigned krem = sel[0];
    unsigned s = 0;
    for (int i = 0; i < bpt; ++i) {
        unsigned bsum = 0;
        for (int j = 0; j < slots; ++j) bsum += hist[(t * bpt + i) * slots + j];
        s += bsum;
    }
    part[t] = s;
    __syncthreads();
    #pragma unroll
    for (int off = 1; off < 256; off <<= 1) {
        unsigned add = (t >= off) ? part[t - off] : 0u;
        __syncthreads();
        part[t] += add;
        __syncthreads();
    }
    unsigned incl = part[t];
    unsigned excl = incl - s;
    if (excl <= krem && krem < incl) { chs = t; runs = excl; }
    __syncthreads();
    int ch = chs;
    if (t < bpt) {
        unsigned g = 0;
        for (int j = 0; j < slots; ++j) g += hist[(ch * bpt + t) * slots + j];
        grp[t] = g;
    }
    __syncthreads();
    if (t == 0) {
        unsigned r2 = runs; int bsel = ch * bpt;
        for (int j = 0; j < bpt; ++j) {
            unsigned h = grp[j];
            if (r2 + h > krem) { bsel = ch * bpt + j; break; }
            r2 += h;
        }
        sel[0] = krem - r2;
        unsigned pref = (sel[1] << bits) | (unsigned)bsel;
        sel[1] = pref;
        if (final_stage) {
            unsigned fb = (pref & 0x80000000u) ? (pref ^ 0x80000000u) : ~pref;
            ((float*)sel)[2] = __uint_as_float(fb);
        }
    }
}

// ---------- K2: threshold + 7x7 maxpool + binarize*R, tile 64x64, 512 threads ----------
__launch_bounds__(512, 6)
__global__ void harris_out(const float* __restrict__ R, const unsigned* __restrict__ sel,
                           float* __restrict__ out) {
    __shared__ __align__(16) float smem2[9520];
    float* SR = smem2;
    float2* SM2 = (float2*)(smem2 + 5040);
    const float med = ((const float*)sel)[2];
    const int tid = threadIdx.x;
    const int x0 = blockIdx.x * 64, y0 = blockIdx.y * 64, b = blockIdx.z;
    const float* Rb = R + (size_t)b * IMH * IMW;

    for (int i = tid; i < 70 * 70; i += 512) {
        int r = i / 70, c = i - r * 70;
        int gy = y0 - 3 + r, gx = x0 - 3 + c;
        float v = -INFINITY;
        if ((unsigned)gy < (unsigned)IMH && (unsigned)gx < (unsigned)IMW)
            v = Rb[(size_t)gy * IMW + gx];
        SR[r * 72 + c] = v;
    }
    __syncthreads();

    for (int i = tid; i < 70 * 32; i += 512) {
        int r = i >> 5, p = i & 31;
        const float2* u = (const float2*)(SR + r * 72 + 2 * p);
        float2 u0 = u[0], u1 = u[1], u2 = u[2], u3 = u[3];
        float cv[8] = {u0.x, u0.y, u1.x, u1.y, u2.x, u2.y, u3.x, u3.y};
        float tv[8];
        #pragma unroll
        for (int k = 0; k < 8; ++k) {
            float v = cv[k];
            tv[k] = (v < med) ? ((v == -INFINITY) ? -INFINITY : 0.0f) : v;
        }
        float mid = fmaxf(fmaxf(fmaxf(tv[1], tv[2]), fmaxf(tv[3], tv[4])), fmaxf(tv[5], tv[6]));
        SM2[r * 32 + p] = make_float2(fmaxf(tv[0], mid), fmaxf(tv[7], mid));
    }
    __syncthreads();

    const int p = tid & 31, g = tid >> 5;
    float2 vm[10];
    #pragma unroll
    for (int t = 0; t < 10; ++t) vm[t] = SM2[(4 * g + t) * 32 + p];
    float2 m2[9];
    #pragma unroll
    for (int i = 0; i < 9; ++i) m2[i] = fmax2(vm[i], vm[i + 1]);
    float2 m4[7];
    #pragma unroll
    for (int i = 0; i < 7; ++i) m4[i] = fmax2(m2[i], m2[i + 2]);
    float* ob = out + (size_t)b * IMH * IMW + (size_t)y0 * IMW + x0;
    #pragma unroll
    for (int j = 0; j < 4; ++j) {
        float2 pooled = fmax2(m4[j], m4[j + 3]);
        float vA = SR[(4 * g + j + 3) * 72 + 2 * p + 3];
        float vB = SR[(4 * g + j + 3) * 72 + 2 * p + 4];
        float tA = (vA < med) ? 0.0f : vA;
        float tB = (vB < med) ? 0.0f : vB;
        float2 o = make_float2((tA == pooled.x) ? vA : 0.0f, (tB == pooled.y) ? vB : 0.0f);
        *(float2*)&ob[(size_t)(4 * g + j) * IMW + 2 * p] = o;
    }
}

extern "C" void kernel_launch(void* const* d_in, const int* in_sizes, int n_in,
                              void* d_out, int out_size, void* d_ws, size_t ws_size,
                              hipStream_t stream) {
    const float* x = (const float*)d_in[0];
    float* out = (float*)d_out;

    // ws: R (64MB) | h1[2048*8] | h2[4096] | h3[512] | sel[8] | [STH if it fits]
    const size_t base_need = (size_t)NPIX * 4 + (16384 + 4096 + 512 + 8) * 4;
    if (ws_size < base_need) return;
    float* R = (float*)d_ws;
    unsigned* hbase = (unsigned*)((char*)d_ws + (size_t)NPIX * 4);
    unsigned* h1 = hbase;            // 16384 (2048 bins x 8 slots)
    unsigned* h2 = hbase + 16384;    // 4096
    unsigned* h3 = hbase + 20480;    // 512
    unsigned* sel = hbase + 20992;   // 8
    float* STH = (float*)((char*)d_ws + ((base_need + 255) & ~(size_t)255));

    int nbands = 0;
    for (int cand = 1; cand <= 4; cand <<= 1) {
        size_t sth_bytes = 12ull * ((IMH / cand) + 6) * IMW * 4;
        if (ws_size >= ((base_need + 255) & ~(size_t)255) + sth_bytes) { nbands = cand; break; }
    }

    zero_kernel<<<(21000 + 255) / 256, 256, 0, stream>>>(hbase, 21000, 20992, KSEL);

    if (nbands) {
        const int band_rows = IMH / nbands;
        const size_t ps = (size_t)(band_rows + 6) * IMW;
        for (int band = 0; band < nbands; ++band) {
            const int bs = band * band_rows;
            const int sr0 = bs - 3, nsr = band_rows + 6;
            dim3 ga(IMW / 64, (nsr + 15) / 16, NB);
            passA<<<ga, 256, 0, stream>>>(x, STH, sr0, nsr, ps);
            dim3 gb(IMW / 512, band_rows / 8, NB);
            passB<<<gb, 256, 0, stream>>>(STH, R, h1, bs, ps);
        }
    } else {
        dim3 rgrid(IMW / 64, IMH / 32, NB);
        harris_R<<<rgrid, 256, 0, stream>>>(x, R, h1);
    }

    select_kernel<<<1, 256, 0, stream>>>(h1, sel, 8, 11, 0, 8);
    hist2_kernel<<<2048, 256, 0, stream>>>(R, h2, sel);
    select_kernel<<<1, 256, 0, stream>>>(h2, sel, 16, 12, 0, 1);
    hist3_kernel<<<2048, 256, 0, stream>>>(R, h3, sel);
    select_kernel<<<1, 256, 0, stream>>>(h3, sel, 2, 9, 1, 1);

    dim3 ogrid(IMW / 64, IMH / 64, NB);
    harris_out<<<ogrid, 512, 0, stream>>>(R, sel, out);
}